// Round 8
// baseline (502.672 us; speedup 1.0000x reference)
//
#include <hip/hip_runtime.h>
#include <hip/hip_bf16.h>

#define N_NODES   100000
#define N_EDGES   1000000
#define N_FEAT    136
#define HIDDEN    64
#define N_CLASSES 2
#define NUM_GRAPHS 512

#define NP_PAD    100352          // 98 * 1024
#define SCAN_BLKS 98

#define CHUNK      16
#define NCHUNK     (N_EDGES / CHUNK)   // 62500 exact
#define SEG_BLOCKS 1280                // 5120 waves, ~12 chunks each

typedef unsigned short ushort_t;

// fp32 -> bf16 (RTNE), bf16 -> fp32
__device__ __forceinline__ ushort_t f2b(float v) {
    unsigned b = __float_as_uint(v);
    return (ushort_t)((b + 0x7FFF + ((b >> 16) & 1)) >> 16);
}
__device__ __forceinline__ float b2f(ushort_t u) {
    return __uint_as_float(((unsigned)u) << 16);
}

// ============================ CSR build =====================================
__global__ __launch_bounds__(256) void hist_kernel(const int* __restrict__ dst,
                                                   int* __restrict__ cnt) {
    int e = blockIdx.x * 256 + threadIdx.x;
    if (e < N_EDGES) atomicAdd(&cnt[dst[e]], 1);
}

__global__ __launch_bounds__(256) void scan1_kernel(const int* __restrict__ cnt,
                                                    int* __restrict__ row_ptr,
                                                    int* __restrict__ partials) {
    __shared__ int sd[256];
    int b = blockIdx.x, t = threadIdx.x;
    int i0 = b * 1024 + t * 4;
    int c0 = (i0 + 0 < N_NODES) ? cnt[i0 + 0] : 0;
    int c1 = (i0 + 1 < N_NODES) ? cnt[i0 + 1] : 0;
    int c2 = (i0 + 2 < N_NODES) ? cnt[i0 + 2] : 0;
    int c3 = (i0 + 3 < N_NODES) ? cnt[i0 + 3] : 0;
    int tsum = c0 + c1 + c2 + c3;
    sd[t] = tsum;
    __syncthreads();
    for (int off = 1; off < 256; off <<= 1) {
        int v = (t >= off) ? sd[t - off] : 0;
        __syncthreads();
        sd[t] += v;
        __syncthreads();
    }
    int excl = sd[t] - tsum;
    row_ptr[i0 + 0] = excl;
    row_ptr[i0 + 1] = excl + c0;
    row_ptr[i0 + 2] = excl + c0 + c1;
    row_ptr[i0 + 3] = excl + c0 + c1 + c2;
    if (t == 255) partials[b] = sd[255];
}

__global__ __launch_bounds__(128) void scan2_kernel(int* __restrict__ partials) {
    __shared__ int sd[128];
    int t = threadIdx.x;
    int v = (t < SCAN_BLKS) ? partials[t] : 0;
    sd[t] = v;
    __syncthreads();
    for (int off = 1; off < 128; off <<= 1) {
        int u = (t >= off) ? sd[t - off] : 0;
        __syncthreads();
        sd[t] += u;
        __syncthreads();
    }
    partials[t] = sd[t] - v;
}

__global__ __launch_bounds__(256) void scan3_kernel(int* __restrict__ row_ptr,
                                                    int* __restrict__ cursor,
                                                    const int* __restrict__ partials) {
    int i = blockIdx.x * 256 + threadIdx.x;
    if (i < N_NODES) {
        int v = row_ptr[i] + partials[i >> 10];
        row_ptr[i] = v;
        cursor[i]  = v;
    }
    if (i == N_NODES) row_ptr[N_NODES] = N_EDGES;
}

// scatter ONLY src (4B) to random CSR position (half the random-write lines)
__global__ __launch_bounds__(256) void scatter_kernel(const int* __restrict__ src,
                                                      const int* __restrict__ dst,
                                                      int* __restrict__ cursor,
                                                      int* __restrict__ csr_src) {
    int e = blockIdx.x * 256 + threadIdx.x;
    if (e < N_EDGES) {
        int pos = atomicAdd(&cursor[dst[e]], 1);
        csr_src[pos] = src[e];
    }
}

// coalesced expansion: dst_sorted[row_ptr[i]..row_ptr[i+1]) = i
__global__ __launch_bounds__(256) void expand_kernel(const int* __restrict__ row_ptr,
                                                     int* __restrict__ dst_sorted) {
    int i = blockIdx.x * 256 + threadIdx.x;
    if (i < N_NODES) {
        int s = row_ptr[i], e = row_ptr[i + 1];
        for (int j = s; j < e; ++j) dst_sorted[j] = i;
    }
}

__global__ __launch_bounds__(256) void dinv_kernel(const int* __restrict__ row_ptr,
                                                   float* __restrict__ dinv) {
    int i = blockIdx.x * 256 + threadIdx.x;
    if (i < N_NODES)
        dinv[i] = rsqrtf((float)(row_ptr[i + 1] - row_ptr[i] + 1));  // +1 self-loop
}

// ---- graph boundaries: gstart[g] = lower_bound(batch, g) -------------------
__global__ __launch_bounds__(256) void gbounds_kernel(const int* __restrict__ batch,
                                                      int* __restrict__ gstart) {
    int g = blockIdx.x * 256 + threadIdx.x;
    if (g > NUM_GRAPHS) return;
    int lo = 0, hi = N_NODES;
    while (lo < hi) {
        int mid = (lo + hi) >> 1;
        if (batch[mid] < g) lo = mid + 1; else hi = mid;
    }
    gstart[g] = lo;
}

// ==================== t' = (x @ W1) * dinv -> bf16  (136 -> 64) =============
// W1 in LDS; x rows read as wave-broadcast float4 global loads (L1-resident)
__global__ __launch_bounds__(256) void mm1_kernel(const float* __restrict__ x,
                                                  const float* __restrict__ W1,
                                                  const float* __restrict__ dinv,
                                                  ushort_t* __restrict__ tpb) {
    __shared__ float Ws[N_FEAT * HIDDEN];        // 34816 B
    int t = threadIdx.x;
    int n0 = blockIdx.x * 16;                    // 6250*16 = 100000 exact
    {
        const float4* W14 = (const float4*)W1;
        float4* Ws4 = (float4*)Ws;
        for (int i = t; i < N_FEAT * HIDDEN / 4; i += 256) Ws4[i] = W14[i];
    }
    __syncthreads();
    int f = t & 63, w = t >> 6;
    int nA = n0 + w, nB = n0 + w + 4, nC = n0 + w + 8, nD = n0 + w + 12;
    const float4* xA = (const float4*)x + (long long)nA * (N_FEAT / 4);
    const float4* xB = (const float4*)x + (long long)nB * (N_FEAT / 4);
    const float4* xC = (const float4*)x + (long long)nC * (N_FEAT / 4);
    const float4* xD = (const float4*)x + (long long)nD * (N_FEAT / 4);
    float a0 = 0.f, a1 = 0.f, a2 = 0.f, a3 = 0.f;
#pragma unroll 2
    for (int k4 = 0; k4 < N_FEAT / 4; ++k4) {
        float4 vA = xA[k4], vB = xB[k4], vC = xC[k4], vD = xD[k4];
        float w0 = Ws[(4 * k4 + 0) * 64 + f];
        float w1 = Ws[(4 * k4 + 1) * 64 + f];
        float w2 = Ws[(4 * k4 + 2) * 64 + f];
        float w3 = Ws[(4 * k4 + 3) * 64 + f];
        a0 += vA.x * w0 + vA.y * w1 + vA.z * w2 + vA.w * w3;
        a1 += vB.x * w0 + vB.y * w1 + vB.z * w2 + vB.w * w3;
        a2 += vC.x * w0 + vC.y * w1 + vC.z * w2 + vC.w * w3;
        a3 += vD.x * w0 + vD.y * w1 + vD.z * w2 + vD.w * w3;
    }
    tpb[nA * 64 + f] = f2b(a0 * dinv[nA]);
    tpb[nB * 64 + f] = f2b(a1 * dinv[nB]);
    tpb[nC * 64 + f] = f2b(a2 * dinv[nC]);
    tpb[nD * 64 + f] = f2b(a3 * dinv[nD]);
}

// ==================== t' = (h @ W2) * dinv -> bf16  (64 -> 64) ==============
__global__ __launch_bounds__(256) void mm2_kernel(const float* __restrict__ h,
                                                  const float* __restrict__ W2,
                                                  const float* __restrict__ dinv,
                                                  ushort_t* __restrict__ tpb) {
    __shared__ float Ws[HIDDEN * HIDDEN];        // 16 KB
    int t = threadIdx.x;
    int n0 = blockIdx.x * 16;
    {
        const float4* W24 = (const float4*)W2;
        float4* Ws4 = (float4*)Ws;
        for (int i = t; i < HIDDEN * HIDDEN / 4; i += 256) Ws4[i] = W24[i];
    }
    __syncthreads();
    int f = t & 63, w = t >> 6;
    int nA = n0 + w, nB = n0 + w + 4, nC = n0 + w + 8, nD = n0 + w + 12;
    const float4* hA = (const float4*)h + nA * (HIDDEN / 4);
    const float4* hB = (const float4*)h + nB * (HIDDEN / 4);
    const float4* hC = (const float4*)h + nC * (HIDDEN / 4);
    const float4* hD = (const float4*)h + nD * (HIDDEN / 4);
    float a0 = 0.f, a1 = 0.f, a2 = 0.f, a3 = 0.f;
#pragma unroll 4
    for (int k4 = 0; k4 < HIDDEN / 4; ++k4) {
        float4 vA = hA[k4], vB = hB[k4], vC = hC[k4], vD = hD[k4];
        float w0 = Ws[(4 * k4 + 0) * 64 + f];
        float w1 = Ws[(4 * k4 + 1) * 64 + f];
        float w2 = Ws[(4 * k4 + 2) * 64 + f];
        float w3 = Ws[(4 * k4 + 3) * 64 + f];
        a0 += vA.x * w0 + vA.y * w1 + vA.z * w2 + vA.w * w3;
        a1 += vB.x * w0 + vB.y * w1 + vB.z * w2 + vB.w * w3;
        a2 += vC.x * w0 + vC.y * w1 + vC.z * w2 + vC.w * w3;
        a3 += vD.x * w0 + vD.y * w1 + vD.z * w2 + vD.w * w3;
    }
    tpb[nA * 64 + f] = f2b(a0 * dinv[nA]);
    tpb[nB * 64 + f] = f2b(a1 * dinv[nB]);
    tpb[nC * 64 + f] = f2b(a2 * dinv[nC]);
    tpb[nD * 64 + f] = f2b(a3 * dinv[nD]);
}

// ======== edge-parallel segmented reduce over CSR (dst-sorted) ==============
__global__ __launch_bounds__(256, 4) void edge_seg_kernel(const int* __restrict__ csr_src,
                                                          const int* __restrict__ dst_sorted,
                                                          const ushort_t* __restrict__ tpb,
                                                          float* __restrict__ agg) {
    int lane = threadIdx.x & 63;
    int wid  = (blockIdx.x * 256 + threadIdx.x) >> 6;
    const int nw = SEG_BLOCKS * 4;               // 5120 waves
    int i16 = lane & 15;

    int sv = csr_src[wid * CHUNK + i16];
    int dv = dst_sorted[wid * CHUNK + i16];
    for (int c = wid; c < NCHUNK; c += nw) {
        int cn = c + nw;
        int sv_next = sv, dv_next = dv;
        if (cn < NCHUNK) {                        // prefetch next chunk's indices
            sv_next = csr_src[cn * CHUNK + i16];
            dv_next = dst_sorted[cn * CHUNK + i16];
        }

        float vv[CHUNK];
        int dd[CHUNK];
#pragma unroll
        for (int j = 0; j < CHUNK; ++j) {
            int s = __builtin_amdgcn_readlane(sv, j);          // scalar src
            dd[j] = __builtin_amdgcn_readlane(dv, j);          // scalar dst
            vv[j] = b2f(tpb[s * 64 + lane]);                   // independent gather
        }
        float acc = vv[0];
        int dprev = dd[0];
#pragma unroll
        for (int j = 1; j < CHUNK; ++j) {
            if (dd[j] != dprev) {                // wave-uniform branch
                atomicAdd(&agg[dprev * 64 + lane], acc);
                acc = 0.0f;
                dprev = dd[j];
            }
            acc += vv[j];
        }
        atomicAdd(&agg[dprev * 64 + lane], acc);
        sv = sv_next; dv = dv_next;
    }
}

// ---- epilogue 1: h = relu((agg + self) * dinv + b) -------------------------
__global__ __launch_bounds__(256) void epi1_kernel(const float* __restrict__ agg,
                                                   const ushort_t* __restrict__ tpb,
                                                   const float* __restrict__ dinv,
                                                   const float* __restrict__ bias,
                                                   float* __restrict__ h) {
    int idx = blockIdx.x * 256 + threadIdx.x;    // 25000 blocks exact
    int n = idx >> 6, f = idx & 63;
    float v = fmaf(agg[idx] + b2f(tpb[idx]), dinv[n], bias[f]);
    h[idx] = fmaxf(v, 0.0f);
}

// ---- layer-2 epilogue fused with pool: one wave per graph, NO atomics ------
__global__ __launch_bounds__(256) void gpool_kernel(const float* __restrict__ agg,
                                                    const ushort_t* __restrict__ tpb,
                                                    const float* __restrict__ dinv,
                                                    const float* __restrict__ bias,
                                                    const int* __restrict__ gstart,
                                                    float* __restrict__ sums,
                                                    float* __restrict__ gcount) {
    int lane = threadIdx.x & 63;
    int g = (blockIdx.x * 256 + threadIdx.x) >> 6;    // 128 blocks * 4 waves = 512
    int s = gstart[g], e = gstart[g + 1];
    float b = bias[lane];
    float acc = 0.0f;
#pragma unroll 4
    for (int n = s; n < e; ++n) {
        int idx = n * 64 + lane;
        float v = fmaxf(fmaf(agg[idx] + b2f(tpb[idx]), dinv[n], b), 0.0f);
        acc += v;
    }
    sums[g * 64 + lane] = acc;
    if (lane == 0) gcount[g] = (float)(e - s);
}

// ---- head: out = (sums/counts) @ Wout + bout -------------------------------
__global__ __launch_bounds__(256) void out_kernel(const float* __restrict__ sums,
                                                  const float* __restrict__ gcount,
                                                  const float* __restrict__ Wout,
                                                  const float* __restrict__ bout,
                                                  float* __restrict__ out) {
    int idx = blockIdx.x * 256 + threadIdx.x;
    if (idx >= NUM_GRAPHS * N_CLASSES) return;
    int g = idx / N_CLASSES, c = idx % N_CLASSES;
    float inv_cnt = 1.0f / fmaxf(gcount[g], 1.0f);
    float acc = 0.0f;
#pragma unroll
    for (int k = 0; k < HIDDEN; ++k)
        acc += sums[g * HIDDEN + k] * Wout[k * N_CLASSES + c];
    out[idx] = acc * inv_cnt + bout[c];
}

extern "C" void kernel_launch(void* const* d_in, const int* in_sizes, int n_in,
                              void* d_out, int out_size, void* d_ws, size_t ws_size,
                              hipStream_t stream) {
    const float* x     = (const float*)d_in[0];
    const int*   ei    = (const int*)d_in[1];
    const int*   batch = (const int*)d_in[2];
    const float* W1    = (const float*)d_in[3];
    const float* b1    = (const float*)d_in[4];
    const float* W2    = (const float*)d_in[5];
    const float* b2    = (const float*)d_in[6];
    const float* Wout  = (const float*)d_in[7];
    const float* bout  = (const float*)d_in[8];
    float* out = (float*)d_out;

    const int* src = ei;
    const int* dst = ei + N_EDGES;

    // -------- workspace layout (~73.5 MB) --------
    char* p = (char*)d_ws;
    int*      row_ptr   = (int*)p;      p += (NP_PAD + 256) * sizeof(int);
    int*      cnt       = (int*)p;      p += NP_PAD * sizeof(int);   // hist, then cursor
    int*      partials  = (int*)p;      p += 256 * sizeof(int);
    int*      gstart    = (int*)p;      p += (NUM_GRAPHS + 64) * sizeof(int);
    int*      csr_src   = (int*)p;      p += (size_t)N_EDGES * sizeof(int);   // 4 MB
    int*      dst_sorted= (int*)p;      p += (size_t)N_EDGES * sizeof(int);   // 4 MB
    float*    dinv      = (float*)p;    p += NP_PAD * sizeof(float);
    ushort_t* tpb       = (ushort_t*)p; p += (size_t)N_NODES * HIDDEN * sizeof(ushort_t);
    float*    hbuf      = (float*)p;    p += (size_t)N_NODES * HIDDEN * sizeof(float);
    float*    agg       = (float*)p;    p += (size_t)N_NODES * HIDDEN * sizeof(float);
    float*    sums      = (float*)p;    p += NUM_GRAPHS * HIDDEN * sizeof(float);
    float*    gcount    = (float*)p;    p += NUM_GRAPHS * sizeof(float);

    const int NB_E  = (N_EDGES + 255) / 256;
    const int NB_N  = (N_NODES + 255) / 256;
    const int NB_MM = N_NODES / 16;           // 6250
    const int NB_EP = N_NODES * HIDDEN / 256; // 25000 exact

    // -------- CSR build + graph bounds --------
    hipMemsetAsync(cnt, 0, NP_PAD * sizeof(int), stream);
    hist_kernel<<<NB_E, 256, 0, stream>>>(dst, cnt);
    scan1_kernel<<<SCAN_BLKS, 256, 0, stream>>>(cnt, row_ptr, partials);
    scan2_kernel<<<1, 128, 0, stream>>>(partials);
    scan3_kernel<<<NP_PAD / 256, 256, 0, stream>>>(row_ptr, cnt, partials);
    scatter_kernel<<<NB_E, 256, 0, stream>>>(src, dst, cnt, csr_src);
    expand_kernel<<<NB_N, 256, 0, stream>>>(row_ptr, dst_sorted);
    dinv_kernel<<<NB_N, 256, 0, stream>>>(row_ptr, dinv);
    gbounds_kernel<<<3, 256, 0, stream>>>(batch, gstart);

    hipMemsetAsync(agg, 0, (size_t)N_NODES * HIDDEN * sizeof(float), stream);

    // -------- layer 1 --------
    mm1_kernel<<<NB_MM, 256, 0, stream>>>(x, W1, dinv, tpb);
    edge_seg_kernel<<<SEG_BLOCKS, 256, 0, stream>>>(csr_src, dst_sorted, tpb, agg);
    epi1_kernel<<<NB_EP, 256, 0, stream>>>(agg, tpb, dinv, b1, hbuf);

    // -------- layer 2 (epilogue + pool fused, no atomics) --------
    mm2_kernel<<<NB_MM, 256, 0, stream>>>(hbuf, W2, dinv, tpb);
    hipMemsetAsync(agg, 0, (size_t)N_NODES * HIDDEN * sizeof(float), stream);
    edge_seg_kernel<<<SEG_BLOCKS, 256, 0, stream>>>(csr_src, dst_sorted, tpb, agg);
    gpool_kernel<<<NUM_GRAPHS / 4, 256, 0, stream>>>(agg, tpb, dinv, b2, gstart,
                                                     sums, gcount);

    // -------- head --------
    out_kernel<<<(NUM_GRAPHS * N_CLASSES + 255) / 256, 256, 0, stream>>>(
        sums, gcount, Wout, bout, out);
}

// Round 9
// 417.334 us; speedup vs baseline: 1.2045x; 1.2045x over previous
//
#include <hip/hip_runtime.h>
#include <hip/hip_bf16.h>

#define N_NODES   100000
#define N_EDGES   1000000
#define N_FEAT    136
#define HIDDEN    64
#define N_CLASSES 2
#define NUM_GRAPHS 512

#define NP_PAD    100352          // 98 * 1024
#define SCAN_BLKS 98

#define CHUNK      16
#define NCHUNK     (N_EDGES / CHUNK)   // 62500 exact
#define SEG_BLOCKS 1280                // 5120 waves, ~12 chunks each

#define K1_4 (N_FEAT / 4)              // 34
#define K2_4 (HIDDEN / 4)              // 16

typedef unsigned short ushort_t;

// fp32 -> bf16 (RTNE), bf16 -> fp32
__device__ __forceinline__ ushort_t f2b(float v) {
    unsigned b = __float_as_uint(v);
    return (ushort_t)((b + 0x7FFF + ((b >> 16) & 1)) >> 16);
}
__device__ __forceinline__ float b2f(ushort_t u) {
    return __uint_as_float(((unsigned)u) << 16);
}
__device__ __forceinline__ unsigned pack2(float a, float b) {
    return (unsigned)f2b(a) | ((unsigned)f2b(b) << 16);
}

// ============================ CSR build =====================================
__global__ __launch_bounds__(256) void hist_kernel(const int* __restrict__ dst,
                                                   int* __restrict__ cnt) {
    int e = blockIdx.x * 256 + threadIdx.x;
    if (e < N_EDGES) atomicAdd(&cnt[dst[e]], 1);
}

__global__ __launch_bounds__(256) void scan1_kernel(const int* __restrict__ cnt,
                                                    int* __restrict__ row_ptr,
                                                    int* __restrict__ partials) {
    __shared__ int sd[256];
    int b = blockIdx.x, t = threadIdx.x;
    int i0 = b * 1024 + t * 4;
    int c0 = (i0 + 0 < N_NODES) ? cnt[i0 + 0] : 0;
    int c1 = (i0 + 1 < N_NODES) ? cnt[i0 + 1] : 0;
    int c2 = (i0 + 2 < N_NODES) ? cnt[i0 + 2] : 0;
    int c3 = (i0 + 3 < N_NODES) ? cnt[i0 + 3] : 0;
    int tsum = c0 + c1 + c2 + c3;
    sd[t] = tsum;
    __syncthreads();
    for (int off = 1; off < 256; off <<= 1) {
        int v = (t >= off) ? sd[t - off] : 0;
        __syncthreads();
        sd[t] += v;
        __syncthreads();
    }
    int excl = sd[t] - tsum;
    row_ptr[i0 + 0] = excl;
    row_ptr[i0 + 1] = excl + c0;
    row_ptr[i0 + 2] = excl + c0 + c1;
    row_ptr[i0 + 3] = excl + c0 + c1 + c2;
    if (t == 255) partials[b] = sd[255];
}

__global__ __launch_bounds__(128) void scan2_kernel(int* __restrict__ partials) {
    __shared__ int sd[128];
    int t = threadIdx.x;
    int v = (t < SCAN_BLKS) ? partials[t] : 0;
    sd[t] = v;
    __syncthreads();
    for (int off = 1; off < 128; off <<= 1) {
        int u = (t >= off) ? sd[t - off] : 0;
        __syncthreads();
        sd[t] += u;
        __syncthreads();
    }
    partials[t] = sd[t] - v;
}

__global__ __launch_bounds__(256) void scan3_kernel(int* __restrict__ row_ptr,
                                                    int* __restrict__ cursor,
                                                    const int* __restrict__ partials) {
    int i = blockIdx.x * 256 + threadIdx.x;
    if (i < N_NODES) {
        int v = row_ptr[i] + partials[i >> 10];
        row_ptr[i] = v;
        cursor[i]  = v;
    }
    if (i == N_NODES) row_ptr[N_NODES] = N_EDGES;
}

// scatter ONLY src (4B) to random CSR position
__global__ __launch_bounds__(256) void scatter_kernel(const int* __restrict__ src,
                                                      const int* __restrict__ dst,
                                                      int* __restrict__ cursor,
                                                      int* __restrict__ csr_src) {
    int e = blockIdx.x * 256 + threadIdx.x;
    if (e < N_EDGES) {
        int pos = atomicAdd(&cursor[dst[e]], 1);
        csr_src[pos] = src[e];
    }
}

// coalesced expansion: dst_sorted[row_ptr[i]..row_ptr[i+1]) = i
__global__ __launch_bounds__(256) void expand_kernel(const int* __restrict__ row_ptr,
                                                     int* __restrict__ dst_sorted) {
    int i = blockIdx.x * 256 + threadIdx.x;
    if (i < N_NODES) {
        int s = row_ptr[i], e = row_ptr[i + 1];
        for (int j = s; j < e; ++j) dst_sorted[j] = i;
    }
}

__global__ __launch_bounds__(256) void dinv_kernel(const int* __restrict__ row_ptr,
                                                   float* __restrict__ dinv) {
    int i = blockIdx.x * 256 + threadIdx.x;
    if (i < N_NODES)
        dinv[i] = rsqrtf((float)(row_ptr[i + 1] - row_ptr[i] + 1));  // +1 self-loop
}

// ---- graph boundaries: gstart[g] = lower_bound(batch, g) -------------------
__global__ __launch_bounds__(256) void gbounds_kernel(const int* __restrict__ batch,
                                                      int* __restrict__ gstart) {
    int g = blockIdx.x * 256 + threadIdx.x;
    if (g > NUM_GRAPHS) return;
    int lo = 0, hi = N_NODES;
    while (lo < hi) {
        int mid = (lo + hi) >> 1;
        if (batch[mid] < g) lo = mid + 1; else hi = mid;
    }
    gstart[g] = lo;
}

// ==================== t' = (x @ W1) * dinv -> bf16  (136 -> 64) =============
// 64-node tile; x staged as bf16 in LDS; thread = 8 nodes x 2 adjacent f.
__global__ __launch_bounds__(256) void mm1_kernel(const float* __restrict__ x,
                                                  const float* __restrict__ W1,
                                                  const float* __restrict__ dinv,
                                                  ushort_t* __restrict__ tpb) {
    __shared__ float    Ws[N_FEAT * HIDDEN];      // 34816 B
    __shared__ unsigned xsb[64 * (N_FEAT / 2)];   // bf16x2, 17408 B
    int t = threadIdx.x;
    int n0 = blockIdx.x * 64;
    {
        const float4* W14 = (const float4*)W1;
        float4* Ws4 = (float4*)Ws;
        for (int i = t; i < N_FEAT * HIDDEN / 4; i += 256) Ws4[i] = W14[i];
        const float4* x4 = (const float4*)x;
        for (int i = t; i < 64 * K1_4; i += 256) {
            int r = i / K1_4, c = i % K1_4;
            int n = n0 + r; if (n >= N_NODES) n = N_NODES - 1;
            float4 v = x4[(long long)n * K1_4 + c];
            xsb[r * (N_FEAT / 2) + 2 * c]     = pack2(v.x, v.y);
            xsb[r * (N_FEAT / 2) + 2 * c + 1] = pack2(v.z, v.w);
        }
    }
    __syncthreads();
    int fg = t & 31;     // f = 2fg, 2fg+1
    int ng = t >> 5;     // nodes ng + 8j
    float acc0[8], acc1[8];
#pragma unroll
    for (int j = 0; j < 8; ++j) { acc0[j] = 0.f; acc1[j] = 0.f; }
    for (int k4 = 0; k4 < K1_4; ++k4) {
        float2 w0 = *(const float2*)&Ws[(4 * k4 + 0) * 64 + 2 * fg];
        float2 w1 = *(const float2*)&Ws[(4 * k4 + 1) * 64 + 2 * fg];
        float2 w2 = *(const float2*)&Ws[(4 * k4 + 2) * 64 + 2 * fg];
        float2 w3 = *(const float2*)&Ws[(4 * k4 + 3) * 64 + 2 * fg];
#pragma unroll
        for (int j = 0; j < 8; ++j) {
            uint2 u = *(const uint2*)&xsb[(ng + 8 * j) * (N_FEAT / 2) + 2 * k4];
            float vx = __uint_as_float(u.x << 16);
            float vy = __uint_as_float(u.x & 0xffff0000u);
            float vz = __uint_as_float(u.y << 16);
            float vw = __uint_as_float(u.y & 0xffff0000u);
            acc0[j] += vx * w0.x + vy * w1.x + vz * w2.x + vw * w3.x;
            acc1[j] += vx * w0.y + vy * w1.y + vz * w2.y + vw * w3.y;
        }
    }
#pragma unroll
    for (int j = 0; j < 8; ++j) {
        int n = n0 + ng + 8 * j;
        if (n < N_NODES) {
            float di = dinv[n];
            ((unsigned*)tpb)[n * 32 + fg] = pack2(acc0[j] * di, acc1[j] * di);
        }
    }
}

// ==================== t' = (h @ W2) * dinv -> bf16  (64 -> 64) ==============
__global__ __launch_bounds__(256) void mm2_kernel(const float* __restrict__ h,
                                                  const float* __restrict__ W2,
                                                  const float* __restrict__ dinv,
                                                  ushort_t* __restrict__ tpb) {
    __shared__ float    Ws[HIDDEN * HIDDEN];      // 16384 B
    __shared__ unsigned hsb[64 * (HIDDEN / 2)];   // bf16x2, 8192 B
    int t = threadIdx.x;
    int n0 = blockIdx.x * 64;
    {
        const float4* W24 = (const float4*)W2;
        float4* Ws4 = (float4*)Ws;
        for (int i = t; i < HIDDEN * HIDDEN / 4; i += 256) Ws4[i] = W24[i];
        const float4* h4 = (const float4*)h;
        for (int i = t; i < 64 * K2_4; i += 256) {
            int r = i / K2_4, c = i % K2_4;
            int n = n0 + r; if (n >= N_NODES) n = N_NODES - 1;
            float4 v = h4[(long long)n * K2_4 + c];
            hsb[r * (HIDDEN / 2) + 2 * c]     = pack2(v.x, v.y);
            hsb[r * (HIDDEN / 2) + 2 * c + 1] = pack2(v.z, v.w);
        }
    }
    __syncthreads();
    int fg = t & 31;
    int ng = t >> 5;
    float acc0[8], acc1[8];
#pragma unroll
    for (int j = 0; j < 8; ++j) { acc0[j] = 0.f; acc1[j] = 0.f; }
    for (int k4 = 0; k4 < K2_4; ++k4) {
        float2 w0 = *(const float2*)&Ws[(4 * k4 + 0) * 64 + 2 * fg];
        float2 w1 = *(const float2*)&Ws[(4 * k4 + 1) * 64 + 2 * fg];
        float2 w2 = *(const float2*)&Ws[(4 * k4 + 2) * 64 + 2 * fg];
        float2 w3 = *(const float2*)&Ws[(4 * k4 + 3) * 64 + 2 * fg];
#pragma unroll
        for (int j = 0; j < 8; ++j) {
            uint2 u = *(const uint2*)&hsb[(ng + 8 * j) * (HIDDEN / 2) + 2 * k4];
            float vx = __uint_as_float(u.x << 16);
            float vy = __uint_as_float(u.x & 0xffff0000u);
            float vz = __uint_as_float(u.y << 16);
            float vw = __uint_as_float(u.y & 0xffff0000u);
            acc0[j] += vx * w0.x + vy * w1.x + vz * w2.x + vw * w3.x;
            acc1[j] += vx * w0.y + vy * w1.y + vz * w2.y + vw * w3.y;
        }
    }
#pragma unroll
    for (int j = 0; j < 8; ++j) {
        int n = n0 + ng + 8 * j;
        if (n < N_NODES) {
            float di = dinv[n];
            ((unsigned*)tpb)[n * 32 + fg] = pack2(acc0[j] * di, acc1[j] * di);
        }
    }
}

// ======== edge-parallel segmented reduce over CSR (dst-sorted) ==============
__global__ __launch_bounds__(256, 4) void edge_seg_kernel(const int* __restrict__ csr_src,
                                                          const int* __restrict__ dst_sorted,
                                                          const ushort_t* __restrict__ tpb,
                                                          float* __restrict__ agg) {
    int lane = threadIdx.x & 63;
    int wid  = (blockIdx.x * 256 + threadIdx.x) >> 6;
    const int nw = SEG_BLOCKS * 4;               // 5120 waves
    int i16 = lane & 15;

    int sv = csr_src[wid * CHUNK + i16];
    int dv = dst_sorted[wid * CHUNK + i16];
    for (int c = wid; c < NCHUNK; c += nw) {
        int cn = c + nw;
        int sv_next = sv, dv_next = dv;
        if (cn < NCHUNK) {                        // prefetch next chunk's indices
            sv_next = csr_src[cn * CHUNK + i16];
            dv_next = dst_sorted[cn * CHUNK + i16];
        }

        float vv[CHUNK];
        int dd[CHUNK];
#pragma unroll
        for (int j = 0; j < CHUNK; ++j) {
            int s = __builtin_amdgcn_readlane(sv, j);          // scalar src
            dd[j] = __builtin_amdgcn_readlane(dv, j);          // scalar dst
            vv[j] = b2f(tpb[s * 64 + lane]);                   // independent gather
        }
        float acc = vv[0];
        int dprev = dd[0];
#pragma unroll
        for (int j = 1; j < CHUNK; ++j) {
            if (dd[j] != dprev) {                // wave-uniform branch
                atomicAdd(&agg[dprev * 64 + lane], acc);
                acc = 0.0f;
                dprev = dd[j];
            }
            acc += vv[j];
        }
        atomicAdd(&agg[dprev * 64 + lane], acc);
        sv = sv_next; dv = dv_next;
    }
}

// ---- epilogue 1: h = relu((agg + self) * dinv + b) -------------------------
__global__ __launch_bounds__(256) void epi1_kernel(const float* __restrict__ agg,
                                                   const ushort_t* __restrict__ tpb,
                                                   const float* __restrict__ dinv,
                                                   const float* __restrict__ bias,
                                                   float* __restrict__ h) {
    int idx = blockIdx.x * 256 + threadIdx.x;    // 25000 blocks exact
    int n = idx >> 6, f = idx & 63;
    float v = fmaf(agg[idx] + b2f(tpb[idx]), dinv[n], bias[f]);
    h[idx] = fmaxf(v, 0.0f);
}

// ---- layer-2 epilogue fused with pool: one wave per graph, NO atomics ------
__global__ __launch_bounds__(256) void gpool_kernel(const float* __restrict__ agg,
                                                    const ushort_t* __restrict__ tpb,
                                                    const float* __restrict__ dinv,
                                                    const float* __restrict__ bias,
                                                    const int* __restrict__ gstart,
                                                    float* __restrict__ sums,
                                                    float* __restrict__ gcount) {
    int lane = threadIdx.x & 63;
    int g = (blockIdx.x * 256 + threadIdx.x) >> 6;    // 128 blocks * 4 waves = 512
    int s = gstart[g], e = gstart[g + 1];
    float b = bias[lane];
    float acc = 0.0f;
#pragma unroll 4
    for (int n = s; n < e; ++n) {
        int idx = n * 64 + lane;
        float v = fmaxf(fmaf(agg[idx] + b2f(tpb[idx]), dinv[n], b), 0.0f);
        acc += v;
    }
    sums[g * 64 + lane] = acc;
    if (lane == 0) gcount[g] = (float)(e - s);
}

// ---- head: out = (sums/counts) @ Wout + bout -------------------------------
__global__ __launch_bounds__(256) void out_kernel(const float* __restrict__ sums,
                                                  const float* __restrict__ gcount,
                                                  const float* __restrict__ Wout,
                                                  const float* __restrict__ bout,
                                                  float* __restrict__ out) {
    int idx = blockIdx.x * 256 + threadIdx.x;
    if (idx >= NUM_GRAPHS * N_CLASSES) return;
    int g = idx / N_CLASSES, c = idx % N_CLASSES;
    float inv_cnt = 1.0f / fmaxf(gcount[g], 1.0f);
    float acc = 0.0f;
#pragma unroll
    for (int k = 0; k < HIDDEN; ++k)
        acc += sums[g * HIDDEN + k] * Wout[k * N_CLASSES + c];
    out[idx] = acc * inv_cnt + bout[c];
}

extern "C" void kernel_launch(void* const* d_in, const int* in_sizes, int n_in,
                              void* d_out, int out_size, void* d_ws, size_t ws_size,
                              hipStream_t stream) {
    const float* x     = (const float*)d_in[0];
    const int*   ei    = (const int*)d_in[1];
    const int*   batch = (const int*)d_in[2];
    const float* W1    = (const float*)d_in[3];
    const float* b1    = (const float*)d_in[4];
    const float* W2    = (const float*)d_in[5];
    const float* b2    = (const float*)d_in[6];
    const float* Wout  = (const float*)d_in[7];
    const float* bout  = (const float*)d_in[8];
    float* out = (float*)d_out;

    const int* src = ei;
    const int* dst = ei + N_EDGES;

    // -------- workspace layout (~73.5 MB) --------
    char* p = (char*)d_ws;
    int*      row_ptr   = (int*)p;      p += (NP_PAD + 256) * sizeof(int);
    int*      cnt       = (int*)p;      p += NP_PAD * sizeof(int);   // hist, then cursor
    int*      partials  = (int*)p;      p += 256 * sizeof(int);
    int*      gstart    = (int*)p;      p += (NUM_GRAPHS + 64) * sizeof(int);
    int*      csr_src   = (int*)p;      p += (size_t)N_EDGES * sizeof(int);   // 4 MB
    int*      dst_sorted= (int*)p;      p += (size_t)N_EDGES * sizeof(int);   // 4 MB
    float*    dinv      = (float*)p;    p += NP_PAD * sizeof(float);
    ushort_t* tpb       = (ushort_t*)p; p += (size_t)N_NODES * HIDDEN * sizeof(ushort_t);
    float*    hbuf      = (float*)p;    p += (size_t)N_NODES * HIDDEN * sizeof(float);
    float*    agg       = (float*)p;    p += (size_t)N_NODES * HIDDEN * sizeof(float);
    float*    sums      = (float*)p;    p += NUM_GRAPHS * HIDDEN * sizeof(float);
    float*    gcount    = (float*)p;    p += NUM_GRAPHS * sizeof(float);

    const int NB_E  = (N_EDGES + 255) / 256;
    const int NB_N  = (N_NODES + 255) / 256;
    const int NB_MM = (N_NODES + 63) / 64;    // 1563 (last block guarded)
    const int NB_EP = N_NODES * HIDDEN / 256; // 25000 exact

    // -------- CSR build + graph bounds --------
    hipMemsetAsync(cnt, 0, NP_PAD * sizeof(int), stream);
    hist_kernel<<<NB_E, 256, 0, stream>>>(dst, cnt);
    scan1_kernel<<<SCAN_BLKS, 256, 0, stream>>>(cnt, row_ptr, partials);
    scan2_kernel<<<1, 128, 0, stream>>>(partials);
    scan3_kernel<<<NP_PAD / 256, 256, 0, stream>>>(row_ptr, cnt, partials);
    scatter_kernel<<<NB_E, 256, 0, stream>>>(src, dst, cnt, csr_src);
    expand_kernel<<<NB_N, 256, 0, stream>>>(row_ptr, dst_sorted);
    dinv_kernel<<<NB_N, 256, 0, stream>>>(row_ptr, dinv);
    gbounds_kernel<<<3, 256, 0, stream>>>(batch, gstart);

    hipMemsetAsync(agg, 0, (size_t)N_NODES * HIDDEN * sizeof(float), stream);

    // -------- layer 1 --------
    mm1_kernel<<<NB_MM, 256, 0, stream>>>(x, W1, dinv, tpb);
    edge_seg_kernel<<<SEG_BLOCKS, 256, 0, stream>>>(csr_src, dst_sorted, tpb, agg);
    epi1_kernel<<<NB_EP, 256, 0, stream>>>(agg, tpb, dinv, b1, hbuf);

    // -------- layer 2 (epilogue + pool fused, no atomics) --------
    mm2_kernel<<<NB_MM, 256, 0, stream>>>(hbuf, W2, dinv, tpb);
    hipMemsetAsync(agg, 0, (size_t)N_NODES * HIDDEN * sizeof(float), stream);
    edge_seg_kernel<<<SEG_BLOCKS, 256, 0, stream>>>(csr_src, dst_sorted, tpb, agg);
    gpool_kernel<<<NUM_GRAPHS / 4, 256, 0, stream>>>(agg, tpb, dinv, b2, gstart,
                                                     sums, gcount);

    // -------- head --------
    out_kernel<<<(NUM_GRAPHS * N_CLASSES + 255) / 256, 256, 0, stream>>>(
        sums, gcount, Wout, bout, out);
}

// Round 10
// 394.983 us; speedup vs baseline: 1.2726x; 1.0566x over previous
//
#include <hip/hip_runtime.h>
#include <hip/hip_bf16.h>

#define N_NODES   100000
#define N_EDGES   1000000
#define N_FEAT    136
#define HIDDEN    64
#define N_CLASSES 2
#define NUM_GRAPHS 512

#define NP_PAD    100352          // 98 * 1024
#define SCAN_BLKS 98

#define CHUNK      16
#define NCHUNK     (N_EDGES / CHUNK)   // 62500 exact
#define SEG_BLOCKS 2048                // 8192 waves = 32/CU capacity

#define XCD        8
#define PART_N     (N_NODES / XCD)     // 12500 exact

#define K1_4 (N_FEAT / 4)              // 34
#define K2_4 (HIDDEN / 4)              // 16

typedef unsigned short ushort_t;

// fp32 -> bf16 (RTNE), bf16 -> fp32
__device__ __forceinline__ ushort_t f2b(float v) {
    unsigned b = __float_as_uint(v);
    return (ushort_t)((b + 0x7FFF + ((b >> 16) & 1)) >> 16);
}
__device__ __forceinline__ float b2f(ushort_t u) {
    return __uint_as_float(((unsigned)u) << 16);
}
__device__ __forceinline__ unsigned pack2(float a, float b) {
    return (unsigned)f2b(a) | ((unsigned)f2b(b) << 16);
}

// ============================ CSR build =====================================
__global__ __launch_bounds__(256) void hist_kernel(const int* __restrict__ dst,
                                                   int* __restrict__ cnt) {
    int e = blockIdx.x * 256 + threadIdx.x;
    if (e < N_EDGES) atomicAdd(&cnt[dst[e]], 1);
}

__global__ __launch_bounds__(256) void scan1_kernel(const int* __restrict__ cnt,
                                                    int* __restrict__ row_ptr,
                                                    int* __restrict__ partials) {
    __shared__ int sd[256];
    int b = blockIdx.x, t = threadIdx.x;
    int i0 = b * 1024 + t * 4;
    int c0 = (i0 + 0 < N_NODES) ? cnt[i0 + 0] : 0;
    int c1 = (i0 + 1 < N_NODES) ? cnt[i0 + 1] : 0;
    int c2 = (i0 + 2 < N_NODES) ? cnt[i0 + 2] : 0;
    int c3 = (i0 + 3 < N_NODES) ? cnt[i0 + 3] : 0;
    int tsum = c0 + c1 + c2 + c3;
    sd[t] = tsum;
    __syncthreads();
    for (int off = 1; off < 256; off <<= 1) {
        int v = (t >= off) ? sd[t - off] : 0;
        __syncthreads();
        sd[t] += v;
        __syncthreads();
    }
    int excl = sd[t] - tsum;
    row_ptr[i0 + 0] = excl;
    row_ptr[i0 + 1] = excl + c0;
    row_ptr[i0 + 2] = excl + c0 + c1;
    row_ptr[i0 + 3] = excl + c0 + c1 + c2;
    if (t == 255) partials[b] = sd[255];
}

__global__ __launch_bounds__(128) void scan2_kernel(int* __restrict__ partials) {
    __shared__ int sd[128];
    int t = threadIdx.x;
    int v = (t < SCAN_BLKS) ? partials[t] : 0;
    sd[t] = v;
    __syncthreads();
    for (int off = 1; off < 128; off <<= 1) {
        int u = (t >= off) ? sd[t - off] : 0;
        __syncthreads();
        sd[t] += u;
        __syncthreads();
    }
    partials[t] = sd[t] - v;
}

__global__ __launch_bounds__(256) void scan3_kernel(int* __restrict__ row_ptr,
                                                    int* __restrict__ cursor,
                                                    const int* __restrict__ partials) {
    int i = blockIdx.x * 256 + threadIdx.x;
    if (i < N_NODES) {
        int v = row_ptr[i] + partials[i >> 10];
        row_ptr[i] = v;
        cursor[i]  = v;
    }
    if (i == N_NODES) row_ptr[N_NODES] = N_EDGES;
}

// XCD-partitioned scatter: partition p (= blockIdx&7) handles dst range
// [p*12500,(p+1)*12500) -> each csr_src line written by one XCD only.
__global__ __launch_bounds__(256) void scatter_kernel(const int* __restrict__ src,
                                                      const int* __restrict__ dst,
                                                      int* __restrict__ cursor,
                                                      int* __restrict__ csr_src) {
    int part = blockIdx.x & (XCD - 1);
    int e = (blockIdx.x >> 3) * 256 + threadIdx.x;
    if (e >= N_EDGES) return;
    int d = dst[e];
    int lo = part * PART_N;
    if (d >= lo && d < lo + PART_N) {
        int pos = atomicAdd(&cursor[d], 1);
        csr_src[pos] = src[e];
    }
}

// coalesced expansion: dst_sorted[row_ptr[i]..row_ptr[i+1]) = i
__global__ __launch_bounds__(256) void expand_kernel(const int* __restrict__ row_ptr,
                                                     int* __restrict__ dst_sorted) {
    int i = blockIdx.x * 256 + threadIdx.x;
    if (i < N_NODES) {
        int s = row_ptr[i], e = row_ptr[i + 1];
        for (int j = s; j < e; ++j) dst_sorted[j] = i;
    }
}

__global__ __launch_bounds__(256) void dinv_kernel(const int* __restrict__ row_ptr,
                                                   float* __restrict__ dinv) {
    int i = blockIdx.x * 256 + threadIdx.x;
    if (i < N_NODES)
        dinv[i] = rsqrtf((float)(row_ptr[i + 1] - row_ptr[i] + 1));  // +1 self-loop
}

// ---- graph boundaries: gstart[g] = lower_bound(batch, g) -------------------
__global__ __launch_bounds__(256) void gbounds_kernel(const int* __restrict__ batch,
                                                      int* __restrict__ gstart) {
    int g = blockIdx.x * 256 + threadIdx.x;
    if (g > NUM_GRAPHS) return;
    int lo = 0, hi = N_NODES;
    while (lo < hi) {
        int mid = (lo + hi) >> 1;
        if (batch[mid] < g) lo = mid + 1; else hi = mid;
    }
    gstart[g] = lo;
}

// ==================== t' = (x @ W1) * dinv -> bf16  (136 -> 64) =============
// 64-node tile; x staged as bf16 in LDS; thread = 8 nodes x 2 adjacent f.
__global__ __launch_bounds__(256) void mm1_kernel(const float* __restrict__ x,
                                                  const float* __restrict__ W1,
                                                  const float* __restrict__ dinv,
                                                  ushort_t* __restrict__ tpb) {
    __shared__ float    Ws[N_FEAT * HIDDEN];      // 34816 B
    __shared__ unsigned xsb[64 * (N_FEAT / 2)];   // bf16x2, 17408 B
    int t = threadIdx.x;
    int n0 = blockIdx.x * 64;
    {
        const float4* W14 = (const float4*)W1;
        float4* Ws4 = (float4*)Ws;
        for (int i = t; i < N_FEAT * HIDDEN / 4; i += 256) Ws4[i] = W14[i];
        const float4* x4 = (const float4*)x;
        for (int i = t; i < 64 * K1_4; i += 256) {
            int r = i / K1_4, c = i % K1_4;
            int n = n0 + r; if (n >= N_NODES) n = N_NODES - 1;
            float4 v = x4[(long long)n * K1_4 + c];
            xsb[r * (N_FEAT / 2) + 2 * c]     = pack2(v.x, v.y);
            xsb[r * (N_FEAT / 2) + 2 * c + 1] = pack2(v.z, v.w);
        }
    }
    __syncthreads();
    int fg = t & 31;     // f = 2fg, 2fg+1
    int ng = t >> 5;     // nodes ng + 8j
    float acc0[8], acc1[8];
#pragma unroll
    for (int j = 0; j < 8; ++j) { acc0[j] = 0.f; acc1[j] = 0.f; }
    for (int k4 = 0; k4 < K1_4; ++k4) {
        float2 w0 = *(const float2*)&Ws[(4 * k4 + 0) * 64 + 2 * fg];
        float2 w1 = *(const float2*)&Ws[(4 * k4 + 1) * 64 + 2 * fg];
        float2 w2 = *(const float2*)&Ws[(4 * k4 + 2) * 64 + 2 * fg];
        float2 w3 = *(const float2*)&Ws[(4 * k4 + 3) * 64 + 2 * fg];
#pragma unroll
        for (int j = 0; j < 8; ++j) {
            uint2 u = *(const uint2*)&xsb[(ng + 8 * j) * (N_FEAT / 2) + 2 * k4];
            float vx = __uint_as_float(u.x << 16);
            float vy = __uint_as_float(u.x & 0xffff0000u);
            float vz = __uint_as_float(u.y << 16);
            float vw = __uint_as_float(u.y & 0xffff0000u);
            acc0[j] += vx * w0.x + vy * w1.x + vz * w2.x + vw * w3.x;
            acc1[j] += vx * w0.y + vy * w1.y + vz * w2.y + vw * w3.y;
        }
    }
#pragma unroll
    for (int j = 0; j < 8; ++j) {
        int n = n0 + ng + 8 * j;
        if (n < N_NODES) {
            float di = dinv[n];
            ((unsigned*)tpb)[n * 32 + fg] = pack2(acc0[j] * di, acc1[j] * di);
        }
    }
}

// ==================== t' = (h @ W2) * dinv -> bf16  (64 -> 64) ==============
__global__ __launch_bounds__(256) void mm2_kernel(const float* __restrict__ h,
                                                  const float* __restrict__ W2,
                                                  const float* __restrict__ dinv,
                                                  ushort_t* __restrict__ tpb) {
    __shared__ float    Ws[HIDDEN * HIDDEN];      // 16384 B
    __shared__ unsigned hsb[64 * (HIDDEN / 2)];   // bf16x2, 8192 B
    int t = threadIdx.x;
    int n0 = blockIdx.x * 64;
    {
        const float4* W24 = (const float4*)W2;
        float4* Ws4 = (float4*)Ws;
        for (int i = t; i < HIDDEN * HIDDEN / 4; i += 256) Ws4[i] = W24[i];
        const float4* h4 = (const float4*)h;
        for (int i = t; i < 64 * K2_4; i += 256) {
            int r = i / K2_4, c = i % K2_4;
            int n = n0 + r; if (n >= N_NODES) n = N_NODES - 1;
            float4 v = h4[(long long)n * K2_4 + c];
            hsb[r * (HIDDEN / 2) + 2 * c]     = pack2(v.x, v.y);
            hsb[r * (HIDDEN / 2) + 2 * c + 1] = pack2(v.z, v.w);
        }
    }
    __syncthreads();
    int fg = t & 31;
    int ng = t >> 5;
    float acc0[8], acc1[8];
#pragma unroll
    for (int j = 0; j < 8; ++j) { acc0[j] = 0.f; acc1[j] = 0.f; }
    for (int k4 = 0; k4 < K2_4; ++k4) {
        float2 w0 = *(const float2*)&Ws[(4 * k4 + 0) * 64 + 2 * fg];
        float2 w1 = *(const float2*)&Ws[(4 * k4 + 1) * 64 + 2 * fg];
        float2 w2 = *(const float2*)&Ws[(4 * k4 + 2) * 64 + 2 * fg];
        float2 w3 = *(const float2*)&Ws[(4 * k4 + 3) * 64 + 2 * fg];
#pragma unroll
        for (int j = 0; j < 8; ++j) {
            uint2 u = *(const uint2*)&hsb[(ng + 8 * j) * (HIDDEN / 2) + 2 * k4];
            float vx = __uint_as_float(u.x << 16);
            float vy = __uint_as_float(u.x & 0xffff0000u);
            float vz = __uint_as_float(u.y << 16);
            float vw = __uint_as_float(u.y & 0xffff0000u);
            acc0[j] += vx * w0.x + vy * w1.x + vz * w2.x + vw * w3.x;
            acc1[j] += vx * w0.y + vy * w1.y + vz * w2.y + vw * w3.y;
        }
    }
#pragma unroll
    for (int j = 0; j < 8; ++j) {
        int n = n0 + ng + 8 * j;
        if (n < N_NODES) {
            float di = dinv[n];
            ((unsigned*)tpb)[n * 32 + fg] = pack2(acc0[j] * di, acc1[j] * di);
        }
    }
}

// ======== edge-parallel segmented reduce over CSR (dst-sorted) ==============
__global__ __launch_bounds__(256, 4) void edge_seg_kernel(const int* __restrict__ csr_src,
                                                          const int* __restrict__ dst_sorted,
                                                          const ushort_t* __restrict__ tpb,
                                                          float* __restrict__ agg) {
    int lane = threadIdx.x & 63;
    int wid  = (blockIdx.x * 256 + threadIdx.x) >> 6;
    const int nw = SEG_BLOCKS * 4;               // 8192 waves
    int i16 = lane & 15;

    int sv = csr_src[wid * CHUNK + i16];
    int dv = dst_sorted[wid * CHUNK + i16];
    for (int c = wid; c < NCHUNK; c += nw) {
        int cn = c + nw;
        int sv_next = sv, dv_next = dv;
        if (cn < NCHUNK) {                        // prefetch next chunk's indices
            sv_next = csr_src[cn * CHUNK + i16];
            dv_next = dst_sorted[cn * CHUNK + i16];
        }

        float vv[CHUNK];
        int dd[CHUNK];
#pragma unroll
        for (int j = 0; j < CHUNK; ++j) {
            int s = __builtin_amdgcn_readlane(sv, j);          // scalar src
            dd[j] = __builtin_amdgcn_readlane(dv, j);          // scalar dst
            vv[j] = b2f(tpb[s * 64 + lane]);                   // independent gather
        }
        float acc = vv[0];
        int dprev = dd[0];
#pragma unroll
        for (int j = 1; j < CHUNK; ++j) {
            if (dd[j] != dprev) {                // wave-uniform branch
                atomicAdd(&agg[dprev * 64 + lane], acc);
                acc = 0.0f;
                dprev = dd[j];
            }
            acc += vv[j];
        }
        atomicAdd(&agg[dprev * 64 + lane], acc);
        sv = sv_next; dv = dv_next;
    }
}

// ---- epilogue 1: h = relu((agg + self) * dinv + b) -------------------------
__global__ __launch_bounds__(256) void epi1_kernel(const float* __restrict__ agg,
                                                   const ushort_t* __restrict__ tpb,
                                                   const float* __restrict__ dinv,
                                                   const float* __restrict__ bias,
                                                   float* __restrict__ h) {
    int idx = blockIdx.x * 256 + threadIdx.x;    // 25000 blocks exact
    int n = idx >> 6, f = idx & 63;
    float v = fmaf(agg[idx] + b2f(tpb[idx]), dinv[n], bias[f]);
    h[idx] = fmaxf(v, 0.0f);
}

// ---- layer-2 epilogue + pool: one BLOCK per graph (4 waves), no atomics ----
__global__ __launch_bounds__(256) void gpool_kernel(const float* __restrict__ agg,
                                                    const ushort_t* __restrict__ tpb,
                                                    const float* __restrict__ dinv,
                                                    const float* __restrict__ bias,
                                                    const int* __restrict__ gstart,
                                                    float* __restrict__ sums,
                                                    float* __restrict__ gcount) {
    __shared__ float red[4][64];
    int lane = threadIdx.x & 63;
    int w = threadIdx.x >> 6;
    int g = blockIdx.x;                      // 512 blocks
    int s = gstart[g], e = gstart[g + 1];
    float b = bias[lane];
    float acc = 0.0f;
    for (int n = s + w; n < e; n += 4) {
        int idx = n * 64 + lane;
        acc += fmaxf(fmaf(agg[idx] + b2f(tpb[idx]), dinv[n], b), 0.0f);
    }
    red[w][lane] = acc;
    __syncthreads();
    if (threadIdx.x < 64) {
        float tot = red[0][lane] + red[1][lane] + red[2][lane] + red[3][lane];
        sums[g * 64 + lane] = tot;
        if (lane == 0) gcount[g] = (float)(e - s);
    }
}

// ---- head: out = (sums/counts) @ Wout + bout -------------------------------
__global__ __launch_bounds__(256) void out_kernel(const float* __restrict__ sums,
                                                  const float* __restrict__ gcount,
                                                  const float* __restrict__ Wout,
                                                  const float* __restrict__ bout,
                                                  float* __restrict__ out) {
    int idx = blockIdx.x * 256 + threadIdx.x;
    if (idx >= NUM_GRAPHS * N_CLASSES) return;
    int g = idx / N_CLASSES, c = idx % N_CLASSES;
    float inv_cnt = 1.0f / fmaxf(gcount[g], 1.0f);
    float acc = 0.0f;
#pragma unroll
    for (int k = 0; k < HIDDEN; ++k)
        acc += sums[g * HIDDEN + k] * Wout[k * N_CLASSES + c];
    out[idx] = acc * inv_cnt + bout[c];
}

extern "C" void kernel_launch(void* const* d_in, const int* in_sizes, int n_in,
                              void* d_out, int out_size, void* d_ws, size_t ws_size,
                              hipStream_t stream) {
    const float* x     = (const float*)d_in[0];
    const int*   ei    = (const int*)d_in[1];
    const int*   batch = (const int*)d_in[2];
    const float* W1    = (const float*)d_in[3];
    const float* b1    = (const float*)d_in[4];
    const float* W2    = (const float*)d_in[5];
    const float* b2    = (const float*)d_in[6];
    const float* Wout  = (const float*)d_in[7];
    const float* bout  = (const float*)d_in[8];
    float* out = (float*)d_out;

    const int* src = ei;
    const int* dst = ei + N_EDGES;

    // -------- workspace layout (~73.5 MB) --------
    char* p = (char*)d_ws;
    int*      row_ptr   = (int*)p;      p += (NP_PAD + 256) * sizeof(int);
    int*      cnt       = (int*)p;      p += NP_PAD * sizeof(int);   // hist, then cursor
    int*      partials  = (int*)p;      p += 256 * sizeof(int);
    int*      gstart    = (int*)p;      p += (NUM_GRAPHS + 64) * sizeof(int);
    int*      csr_src   = (int*)p;      p += (size_t)N_EDGES * sizeof(int);   // 4 MB
    int*      dst_sorted= (int*)p;      p += (size_t)N_EDGES * sizeof(int);   // 4 MB
    float*    dinv      = (float*)p;    p += NP_PAD * sizeof(float);
    ushort_t* tpb       = (ushort_t*)p; p += (size_t)N_NODES * HIDDEN * sizeof(ushort_t);
    float*    hbuf      = (float*)p;    p += (size_t)N_NODES * HIDDEN * sizeof(float);
    float*    agg       = (float*)p;    p += (size_t)N_NODES * HIDDEN * sizeof(float);
    float*    sums      = (float*)p;    p += NUM_GRAPHS * HIDDEN * sizeof(float);
    float*    gcount    = (float*)p;    p += NUM_GRAPHS * sizeof(float);

    const int NB_E  = (N_EDGES + 255) / 256;
    const int NB_N  = (N_NODES + 255) / 256;
    const int NB_MM = (N_NODES + 63) / 64;    // 1563 (last block guarded)
    const int NB_EP = N_NODES * HIDDEN / 256; // 25000 exact

    // -------- CSR build + graph bounds --------
    hipMemsetAsync(cnt, 0, NP_PAD * sizeof(int), stream);
    hist_kernel<<<NB_E, 256, 0, stream>>>(dst, cnt);
    scan1_kernel<<<SCAN_BLKS, 256, 0, stream>>>(cnt, row_ptr, partials);
    scan2_kernel<<<1, 128, 0, stream>>>(partials);
    scan3_kernel<<<NP_PAD / 256, 256, 0, stream>>>(row_ptr, cnt, partials);
    scatter_kernel<<<XCD * NB_E, 256, 0, stream>>>(src, dst, cnt, csr_src);
    expand_kernel<<<NB_N, 256, 0, stream>>>(row_ptr, dst_sorted);
    dinv_kernel<<<NB_N, 256, 0, stream>>>(row_ptr, dinv);
    gbounds_kernel<<<3, 256, 0, stream>>>(batch, gstart);

    hipMemsetAsync(agg, 0, (size_t)N_NODES * HIDDEN * sizeof(float), stream);

    // -------- layer 1 --------
    mm1_kernel<<<NB_MM, 256, 0, stream>>>(x, W1, dinv, tpb);
    edge_seg_kernel<<<SEG_BLOCKS, 256, 0, stream>>>(csr_src, dst_sorted, tpb, agg);
    epi1_kernel<<<NB_EP, 256, 0, stream>>>(agg, tpb, dinv, b1, hbuf);

    // -------- layer 2 (epilogue + pool fused, no atomics) --------
    mm2_kernel<<<NB_MM, 256, 0, stream>>>(hbuf, W2, dinv, tpb);
    hipMemsetAsync(agg, 0, (size_t)N_NODES * HIDDEN * sizeof(float), stream);
    edge_seg_kernel<<<SEG_BLOCKS, 256, 0, stream>>>(csr_src, dst_sorted, tpb, agg);
    gpool_kernel<<<NUM_GRAPHS, 256, 0, stream>>>(agg, tpb, dinv, b2, gstart,
                                                 sums, gcount);

    // -------- head --------
    out_kernel<<<(NUM_GRAPHS * N_CLASSES + 255) / 256, 256, 0, stream>>>(
        sums, gcount, Wout, bout, out);
}